// Round 6
// baseline (773.625 us; speedup 1.0000x reference)
//
#include <hip/hip_runtime.h>

// GRU4REC v9: two independent recurrences interleaved per wave (T15-style).
// B=1024, T=256, D=64, H=128. 128 blocks x 256 threads (4 waves, 1/SIMD),
// 8 rows/block = 2 groups x 4 rows. Wave w owns cols [32w,32w+32) of r/u/c
// for BOTH groups; weight B-frags shared.
// (Resubmit: Round-5 bench failed with GPUAcquisitionTimeout — no data.)
//
// v8 -> v9 (theory: ~60% of the step is exposed wait — in-order 1-wave/SIMD
// has nothing to issue during LDS/MFMA/transcendental/barrier latency.
// Interleaving a second independent 4-row recurrence in the same wave fills
// the stalls and halves the per-row barrier cost):
//  * 2 groups per block; both phases process G0+G1 between the same
//    2 barriers/step. Compiler list-scheduling interleaves the streams.
//  * x via v5 register pipeline (2-deep, parity swap); commit late in P2
//    (~1 step after issue). No XT, no prologue mega-gather.
//  * Bias as persistent C-seed regs (no per-step accumulator-init movs).
//  * v7's conflict-free LDS layouts (SROW=208) retained; plain 6/4-deep
//    chains (v8 split was null).
// LDS: (XA+XC) x 2 groups = 26.6 KiB.

#define T_   256
#define D_   64
#define H_   128
#define SROW 208   // halves per A-row (416 B) — measured conflict-free

typedef _Float16 half8_t  __attribute__((ext_vector_type(8)));
typedef float    floatx4  __attribute__((ext_vector_type(4)));

__device__ __forceinline__ float fast_sigmoid(float x) {
    return __builtin_amdgcn_rcpf(1.f + __expf(-x));   // ~1 ulp, ok vs fp16
}
__device__ __forceinline__ float fast_tanh(float s) {
    s = fminf(fmaxf(s, -15.f), 15.f);
    return 1.f - 2.f * __builtin_amdgcn_rcpf(1.f + __expf(2.f * s));
}

__global__ __launch_bounds__(256, 1) void gru_mfma(
    const int* __restrict__ item_his,          // [1024][256]
    const int* __restrict__ seq_lens,          // [1024]
    const float* __restrict__ emb,             // [1e6][64]
    const float* __restrict__ Wg,              // [192][256]
    const float* __restrict__ bg,              // [256]
    const float* __restrict__ Wc,              // [192][128]
    const float* __restrict__ bc,              // [128]
    float* __restrict__ out)                   // [1024][128] fp32
{
    __shared__ __align__(16) _Float16 XA[2][16][SROW];  // [g]: [x | h]
    __shared__ __align__(16) _Float16 XC[2][16][SROW];  // [g]: [r*h | pad]

    const int tid  = threadIdx.x;
    const int w    = tid >> 6;        // wave 0..3
    const int lane = tid & 63;
    const int row0 = blockIdx.x * 8;  // 8 rows/block

    const int bq = lane >> 4;         // k-quad
    const int bn = lane & 15;         // n within tile / A-row

    // ---- persistent B-fragments: wave w owns N-tiles (2w, 2w+1) ----
    half8_t BG0[2][6], BG1[2][6], BC6[2][6];
    #pragma unroll
    for (int j = 0; j < 2; ++j) {
        const int col = (2 * w + j) * 16 + bn;
        #pragma unroll
        for (int kt = 0; kt < 6; ++kt) {
            half8_t f0, f1, fc;
            #pragma unroll
            for (int i = 0; i < 8; ++i) {
                const int k = kt * 32 + bq * 8 + i;
                f0[i] = (_Float16)Wg[k * 256 + col];
                f1[i] = (_Float16)Wg[k * 256 + 128 + col];
                fc[i] = (_Float16)Wc[k * 128 + col];
            }
            BG0[j][kt] = f0; BG1[j][kt] = f1; BC6[j][kt] = fc;
        }
    }

    // ---- bias C-seeds (persistent; no per-step init movs) ----
    floatx4 cbR[2], cbU[2], cbC[2];
    #pragma unroll
    for (int j = 0; j < 2; ++j) {
        const int col = (2 * w + j) * 16 + bn;
        const float r_ = bg[col], u_ = bg[128 + col], c_ = bc[col];
        cbR[j] = (floatx4){r_, r_, r_, r_};
        cbU[j] = (floatx4){u_, u_, u_, u_};
        cbC[j] = (floatx4){c_, c_, c_, c_};
    }

    // ---- sequence lengths (2 groups x 4 rows) ----
    int len[2][4];
    int maxlen = 0;
    #pragma unroll
    for (int g = 0; g < 2; ++g)
        #pragma unroll
        for (int r = 0; r < 4; ++r) {
            len[g][r] = seq_lens[row0 + 4 * g + r];
            maxlen = max(maxlen, len[g][r]);
        }

    // ---- zero A-buffers (pad rows stay zero forever) ----
    {
        unsigned* pa = (unsigned*)&XA[0][0][0];
        unsigned* pc = (unsigned*)&XC[0][0][0];
        for (int i = tid; i < 2 * 16 * SROW / 2; i += 256) { pa[i] = 0u; pc[i] = 0u; }
    }
    __syncthreads();

    // ---- x register pipeline: wave w <-> row w of each group ----
    // Each lane loads emb[idx][lane] (64 lanes = one 256B coalesced row).
    int   ib[2];
    float xA[2] = {0.f, 0.f}, xB[2] = {0.f, 0.f};
    int   iN[2] = {0, 0},     iM[2] = {0, 0};
    #pragma unroll
    for (int g = 0; g < 2; ++g) ib[g] = (row0 + 4 * g + w) * T_;

    if (maxlen > 0) {
        #pragma unroll
        for (int g = 0; g < 2; ++g) {
            const int i0 = item_his[ib[g] + 0];
            const int i1 = item_his[ib[g] + 1];
            iN[g] = item_his[ib[g] + 2];                     // idx_2
            const float x0 = emb[(size_t)i0 * D_ + lane];
            xA[g] = emb[(size_t)i1 * D_ + lane];             // x_1
            XA[g][w][lane] = (_Float16)x0;                   // commit x_0
        }
    }
    float h[2][2][4];   // [g][j][r]
    float u[2][2][4];
    #pragma unroll
    for (int g = 0; g < 2; ++g)
        #pragma unroll
        for (int j = 0; j < 2; ++j)
            #pragma unroll
            for (int r = 0; r < 4; ++r) { h[g][j][r] = 0.f; u[g][j][r] = 0.f; }
    floatx4 pAC[2][2];  // cand x-partial, carried P1 -> P2
    __syncthreads();

    auto step = [&](int t, float (&xNow)[2], float (&xNew)[2],
                    int (&jNow)[2], int (&jNew)[2]) {
        // ================= Phase 1: gate (both groups) =================
        // issue x_{t+2} + idx_{t+3} prefetch for both groups
        #pragma unroll
        for (int g = 0; g < 2; ++g) {
            xNew[g] = emb[(size_t)jNow[g] * D_ + lane];
            const int t3 = (t + 3 < T_) ? (t + 3) : (T_ - 1);
            jNew[g] = item_his[ib[g] + t3];
        }
        half8_t af[2][6];
        #pragma unroll
        for (int g = 0; g < 2; ++g)
            #pragma unroll
            for (int kt = 0; kt < 6; ++kt)
                af[g][kt] = *(const half8_t*)&XA[g][bn][kt * 32 + bq * 8];

        floatx4 aR[2][2], aU[2][2];
        #pragma unroll
        for (int g = 0; g < 2; ++g)
            #pragma unroll
            for (int j = 0; j < 2; ++j) {
                floatx4 r_ = cbR[j], u_ = cbU[j], cx = cbC[j];
                #pragma unroll
                for (int kt = 0; kt < 6; ++kt) {
                    r_ = __builtin_amdgcn_mfma_f32_16x16x32_f16(af[g][kt], BG0[j][kt], r_, 0, 0, 0);
                    u_ = __builtin_amdgcn_mfma_f32_16x16x32_f16(af[g][kt], BG1[j][kt], u_, 0, 0, 0);
                    if (kt < 2)
                        cx = __builtin_amdgcn_mfma_f32_16x16x32_f16(af[g][kt], BC6[j][kt], cx, 0, 0, 0);
                }
                aR[g][j] = r_; aU[g][j] = u_; pAC[g][j] = cx;
            }
        // r-act + r*h exchange write; u-sigmoid here too (balances phases)
        if (lane < 16) {
            #pragma unroll
            for (int g = 0; g < 2; ++g)
                #pragma unroll
                for (int j = 0; j < 2; ++j)
                    #pragma unroll
                    for (int r = 0; r < 4; ++r) {
                        const float rg = fast_sigmoid(aR[g][j][r]);
                        u[g][j][r]     = fast_sigmoid(aU[g][j][r]);
                        XC[g][r][(2 * w + j) * 16 + lane] = (_Float16)(rg * h[g][j][r]);
                    }
        }
        __syncthreads();

        // ================= Phase 2: cand + h update (both groups) ==========
        half8_t cf[2][4];
        #pragma unroll
        for (int g = 0; g < 2; ++g)
            #pragma unroll
            for (int kk = 0; kk < 4; ++kk)
                cf[g][kk] = *(const half8_t*)&XC[g][bn][kk * 32 + bq * 8];

        floatx4 aC[2][2];
        #pragma unroll
        for (int g = 0; g < 2; ++g)
            #pragma unroll
            for (int j = 0; j < 2; ++j) {
                floatx4 c_ = pAC[g][j];
                #pragma unroll
                for (int kk = 0; kk < 4; ++kk)
                    c_ = __builtin_amdgcn_mfma_f32_16x16x32_f16(cf[g][kk], BC6[j][kk + 2], c_, 0, 0, 0);
                aC[g][j] = c_;
            }
        // commit x_{t+1} late (loads are ~1 full step old here)
        XA[0][w][lane] = (_Float16)xNow[0];
        XA[1][w][lane] = (_Float16)xNow[1];

        if (lane < 16) {
            #pragma unroll
            for (int g = 0; g < 2; ++g)
                #pragma unroll
                for (int j = 0; j < 2; ++j)
                    #pragma unroll
                    for (int r = 0; r < 4; ++r) {
                        const float c  = fast_tanh(aC[g][j][r]);
                        const float hn = c + u[g][j][r] * (h[g][j][r] - c);
                        if (t < len[g][r]) h[g][j][r] = hn;   // copy-through
                        XA[g][r][64 + (2 * w + j) * 16 + lane] = (_Float16)h[g][j][r];
                    }
        }
        __syncthreads();
    };

    // parity-unrolled loop: register slots swap roles (no rotate copies)
    int t = 0;
    while (t < maxlen) {
        step(t, xA, xB, iN, iM);
        ++t;
        if (t >= maxlen) break;
        step(t, xB, xA, iM, iN);
        ++t;
    }

    // ---- write final h (fp32) ----
    if (lane < 16) {
        #pragma unroll
        for (int g = 0; g < 2; ++g)
            #pragma unroll
            for (int j = 0; j < 2; ++j)
                #pragma unroll
                for (int r = 0; r < 4; ++r)
                    out[(row0 + 4 * g + r) * H_ + (2 * w + j) * 16 + lane] = h[g][j][r];
    }
}

extern "C" void kernel_launch(void* const* d_in, const int* in_sizes, int n_in,
                              void* d_out, int out_size, void* d_ws, size_t ws_size,
                              hipStream_t stream) {
    const int*   item_his = (const int*)d_in[0];
    const int*   seq_lens = (const int*)d_in[1];
    const float* emb      = (const float*)d_in[2];
    const float* Wg       = (const float*)d_in[3];
    const float* bg       = (const float*)d_in[4];
    const float* Wc       = (const float*)d_in[5];
    const float* bc       = (const float*)d_in[6];
    float*       out      = (float*)d_out;

    gru_mfma<<<128, 256, 0, stream>>>(item_his, seq_lens, emb, Wg, bg, Wc, bc, out);
}